// Round 3
// baseline (2906.251 us; speedup 1.0000x reference)
//
#include <hip/hip_runtime.h>
#include <cstdint>
#include <cstddef>

#define Bsz 2048
#define Tseq 60
#define Fin 89
#define Hd 1024
#define G4 4096
#define KXP 128   // x/W K padded to 2x BK=64 so all rounds are uniform
#define NOUT 30

typedef _Float16 half8 __attribute__((ext_vector_type(8)));
typedef float f32x4 __attribute__((ext_vector_type(4)));

__device__ __forceinline__ void gload_lds16(const void* g, void* l) {
  __builtin_amdgcn_global_load_lds((const __attribute__((address_space(1))) void*)g,
                                   (__attribute__((address_space(3))) void*)l,
                                   16, 0, 0);
}

__device__ __forceinline__ float sigmoidf_fast(float x) {
  return 1.0f / (1.0f + __expf(-x));
}

// ---------------------------------------------------------------------------
// Prep kernels (run once per launch; ws is re-poisoned before every call)
// ---------------------------------------------------------------------------

// x [B][T][Fin] fp32 -> xp [T][B][KXP] fp16, zero-padded k in [Fin, KXP)
__global__ __launch_bounds__(256) void convert_x(const float* __restrict__ x,
                                                 _Float16* __restrict__ xp) {
  int idx = blockIdx.x * 256 + threadIdx.x;   // < Tseq*Bsz*KXP
  int k = idx % KXP;
  int b = (idx / KXP) % Bsz;
  int t = idx / (KXP * Bsz);
  float v = (k < Fin) ? x[((size_t)b * Tseq + t) * Fin + k] : 0.0f;
  xp[idx] = (_Float16)v;
}

// W [Fin][G4] fp32 -> Wpt [G4][KXP] fp16 (B^T layout, zero rows k>=Fin)
__global__ __launch_bounds__(256) void transpose_W(const float* __restrict__ W,
                                                   _Float16* __restrict__ Wpt) {
  __shared__ float tile[32][33];
  int n0 = blockIdx.x * 32;
  int k0 = blockIdx.y * 32;
  int tx = threadIdx.x, ty = threadIdx.y;
  for (int i = ty; i < 32; i += 8) {
    int k = k0 + i;
    tile[i][tx] = (k < Fin) ? W[(size_t)k * G4 + n0 + tx] : 0.0f;
  }
  __syncthreads();
  for (int i = ty; i < 32; i += 8)
    Wpt[(size_t)(n0 + i) * KXP + k0 + tx] = (_Float16)tile[tx][i];
}

// U [Hd][G4] fp32 -> Upt [G4][Hd] fp16 (B^T layout)
__global__ __launch_bounds__(256) void transpose_U(const float* __restrict__ U,
                                                   _Float16* __restrict__ Upt) {
  __shared__ float tile[32][33];
  int n0 = blockIdx.x * 32;
  int k0 = blockIdx.y * 32;
  int tx = threadIdx.x, ty = threadIdx.y;
  for (int i = ty; i < 32; i += 8)
    tile[i][tx] = U[(size_t)(k0 + i) * G4 + n0 + tx];
  __syncthreads();
  for (int i = ty; i < 32; i += 8)
    Upt[(size_t)(n0 + i) * Hd + k0 + tx] = (_Float16)tile[tx][i];
}

// ---------------------------------------------------------------------------
// One LSTM step. Block tile: 128 batch rows x [4 gates x 32 hidden units].
// Wave w: rows 64*(w>>1)..+63, hidden units j0+16*(w&1)..+15, all 4 gates.
//
// NEW vs previous version (LDS was the binding pipe at 2040 cyc/round/CU):
//   - A-fragments load DIRECTLY global->VGPR (the MFMA a-frag layout is
//     16 rows x 64B contiguous per wave -- naturally coalesced). Double-
//     buffered in registers (arA/arB, static indexing), pipelined by the
//     compiler's exact vmcnt tracking. No barrier dependency.
//   - B keeps the swizzled LDS-DMA path, but fragment reads are inline-asm
//     ds_read_b128: opaque to hipcc's alias analysis, so it CANNOT insert a
//     conservative vmcnt(0) drain; the hand-counted `s_waitcnt vmcnt(12)`
//     (8 A-loads + 4 B-DMA in flight per wave) is the only B-DMA wait.
//   - LDS per round: 64 KB reads + 32 KB writes (~1000 cyc) vs 2040 before;
//     new binding pipe is MFMA (1240 cyc/round/CU).
//   - LDS/block drops 64->32 KB: 3-5 blocks/CU can co-reside (cross-block
//     overlap even if barrier cadences phase-lock).
//
// B LDS layout (unchanged, conflict-free): 16-row unit = 16 rows x 32 halfs,
// slot s of row r holds global chunk s ^ ((r>>1)&3); fragment read slot
// sA = quad ^ ((l16>>1)&3) -> perfect permutation, 2 accesses/bank.
// ---------------------------------------------------------------------------
__global__ __launch_bounds__(256, 2) void lstm_step(
    const _Float16* __restrict__ xp_t,  // [Bsz][KXP]  (this timestep)
    const _Float16* __restrict__ Wpt,   // [G4][KXP]   (B^T)
    const _Float16* __restrict__ Upt,   // [G4][Hd]    (B^T)
    const float*    __restrict__ bias,  // [G4]
    const _Float16* __restrict__ h_in,  // [Bsz][Hd]
    _Float16*       __restrict__ h_out, // [Bsz][Hd]
    float*          __restrict__ cst,   // [Bsz][Hd]
    int skip_h)                          // t==0: only x@W, c_prev = 0
{
  __shared__ __align__(16) _Float16 Bs[2 * 8192];  // 2 buf x (2 subtiles x 8 units) = 32 KB

  const int tid  = threadIdx.x;
  const int wave = tid >> 6;
  const int lane = tid & 63;
  const int quad = lane >> 4;
  const int l16  = lane & 15;

  // XCD-aware bijective swizzle (512 blocks, 8 XCDs round-robin):
  // XCD k gets virt in [64k,64k+64) = j-panels 4k..4k+3 x all 16 m-panels,
  // so each XCD's U slice (1.2 MB) stays L2-resident across rounds & steps.
  const int id   = blockIdx.x;
  const int virt = (id & 7) * 64 + (id >> 3);
  const int m0 = (virt & 15) * 128;   // batch-row base
  const int j0 = (virt >> 4) * 32;    // hidden-unit base

  const int srow = lane >> 2;                      // B staging row in unit
  const int qg   = (lane & 3) ^ ((lane >> 3) & 3); // B staging global chunk
  const int sA   = quad ^ ((l16 >> 1) & 3);        // B fragment LDS slot

  const int hb    = 16 * (wave & 1);
  const int mwave = 64 * (wave >> 1);
  const int j  = j0 + hb + l16;
  const int uA = 4 * (wave >> 1);     // A fragment unit base (+mi)
  const int uB = wave & 1;            // B fragment unit base (2p + uB)
  const int aoff = l16 * 32 + sA * 8; // B fragment offset within unit (halfs)

  float bv[4];
  for (int p = 0; p < 4; ++p) bv[p] = bias[p * Hd + j];

  f32x4 acc[4][4];
  for (int mi = 0; mi < 4; ++mi)
    for (int p = 0; p < 4; ++p)
      acc[mi][p] = f32x4{bv[p], bv[p], bv[p], bv[p]};

  // ---- B: stage one round's 16 KB tile into LDS buffer `buf` (async DMA).
  // Exactly 4 global_load_lds per WAVE -> vmcnt granularity.
  auto stageB = [&](int buf, int r) {
    const _Float16* Bb; int strB, k0;
    if (r < 2) { Bb = Wpt; strB = KXP; k0 = r * 64; }
    else       { Bb = Upt; strB = Hd;  k0 = (r - 2) * 64; }
    _Float16* Bd = &Bs[buf * 8192];
#pragma unroll
    for (int ii = 0; ii < 4; ++ii) {
      int i = ii * 4 + wave;             // 0..15
      int st = i >> 3, ci = i & 7;
      int ln = ci * 16 + srow;
      int gn = (ln >> 5) * Hd + j0 + (ln & 31);   // gate-major B rows
      gload_lds16(Bb + (size_t)gn * strB + k0 + st * 32 + qg * 8,
                  Bd + st * 4096 + ci * 512);
    }
  };

  // ---- A: load this wave's 8 a-fragments for round r straight into VGPRs.
  // lane(quad,l16), frag(mi,st) = A[m0+(uA+mi)*16+l16][k0+st*32+quad*8 ..+7]
  // = 16 rows x 64 B contiguous per wave -> coalesced dwordx4.
  auto loadA = [&](half8 (&ar)[8], int r) {
    const _Float16* Ab; int strA, k0;
    if (r < 2) { Ab = xp_t; strA = KXP; k0 = r * 64; }
    else       { Ab = h_in; strA = Hd;  k0 = (r - 2) * 64; }
    const _Float16* base = Ab + (size_t)(m0 + uA * 16 + l16) * strA + k0 + quad * 8;
#pragma unroll
    for (int mi = 0; mi < 4; ++mi)
#pragma unroll
      for (int st = 0; st < 2; ++st)
        ar[mi * 2 + st] = *(const half8*)(base + (size_t)mi * 16 * strA + st * 32);
  };

  // ---- consume buffer `buf`: 8 asm ds_read_b128 (compiler-opaque) + 32 MFMA
  auto computeC = [&](const half8 (&ar)[8], int buf) {
    const __attribute__((address_space(3))) _Float16* bs3 =
        (const __attribute__((address_space(3))) _Float16*)&Bs[buf * 8192];
    half8 bq[8];
#pragma unroll
    for (int st = 0; st < 2; ++st)
#pragma unroll
      for (int p = 0; p < 4; ++p)
        asm volatile("ds_read_b128 %0, %1"
                     : "=v"(bq[st * 4 + p])
                     : "v"(bs3 + st * 4096 + (2 * p + uB) * 512 + aoff)
                     : "memory");
    asm volatile("s_waitcnt lgkmcnt(0)" ::: "memory");
    __builtin_amdgcn_sched_barrier(0);   // rule #18: pin MFMAs below the wait
#pragma unroll
    for (int st = 0; st < 2; ++st)
#pragma unroll
      for (int mi = 0; mi < 4; ++mi)
#pragma unroll
        for (int p = 0; p < 4; ++p)
          acc[mi][p] = __builtin_amdgcn_mfma_f32_16x16x32_f16(
              ar[mi * 2 + st], bq[st * 4 + p], acc[mi][p], 0, 0, 0);
  };

  const int NR = skip_h ? 2 : 18;

  // Prologue (issue order matters for vmcnt counting):
  stageB(0, 0);          // 4 VMEM
  half8 arA[8], arB[8];
  loadA(arA, 0);         // 8 VMEM
  stageB(1, 1);          // 4 VMEM  -> 16 outstanding

  // Steady-state at top of iter r: outstanding = B(r)[4] + a(r)[8] + B(r+1)[4].
  // vmcnt(12) -> B(r) landed; a(r) waited by compiler's exact count (12) just
  // before the MFMAs; a(r+1)/B(r+1) stay in flight across the barrier.
  auto iter = [&](int r, int buf, const half8 (&acur)[8], half8 (&anxt)[8]) {
    if (r < NR - 1) asm volatile("s_waitcnt vmcnt(12)" ::: "memory");
    else            asm volatile("s_waitcnt vmcnt(0)"  ::: "memory");
    __builtin_amdgcn_sched_barrier(0);
    __builtin_amdgcn_s_barrier();        // all waves: Bs[buf] ready
    if (r + 1 < NR) loadA(anxt, r + 1);  // prefetch next A into regs
    __builtin_amdgcn_s_setprio(1);
    computeC(acur, buf);
    __builtin_amdgcn_s_setprio(0);
    __builtin_amdgcn_s_barrier();        // all waves done reading Bs[buf]
    if (r + 2 < NR) stageB(buf, r + 2);  // restage (in flight next round)
  };

  for (int r = 0; r < NR; r += 2) {      // NR is even (2 or 18)
    iter(r,     0, arA, arB);
    iter(r + 1, 1, arB, arA);
  }

  // epilogue: lane holds i,f,g,o for hidden unit j, rows quad*4+r (m89 layout)
  for (int mi = 0; mi < 4; ++mi) {
    for (int r = 0; r < 4; ++r) {
      int row = m0 + mwave + mi * 16 + quad * 4 + r;
      size_t idx = (size_t)row * Hd + j;
      float iv = sigmoidf_fast(acc[mi][0][r]);
      float fv = sigmoidf_fast(acc[mi][1][r]);
      float gv = fmaxf(acc[mi][2][r], 0.0f);   // relu candidate
      float ov = sigmoidf_fast(acc[mi][3][r]);
      float cprev = skip_h ? 0.0f : cst[idx];  // c_0 = 0 folded in
      float cv = fv * cprev + iv * gv;
      cst[idx] = cv;
      float hv = ov * fmaxf(cv, 0.0f);         // relu on cell output
      h_out[idx] = (_Float16)hv;
    }
  }
}

// ---------------------------------------------------------------------------
// y[b][o] = bd[o] + sum_k h[b][k] * Wd[k][o]
// ---------------------------------------------------------------------------
__global__ __launch_bounds__(256) void final_dense(const _Float16* __restrict__ h,
                                                   const float* __restrict__ Wd,
                                                   const float* __restrict__ bd,
                                                   float* __restrict__ y) {
  __shared__ float hs[Hd];
  __shared__ float red[8][32];
  int bi = blockIdx.x;
  for (int k = threadIdx.x; k < Hd; k += 256)
    hs[k] = (float)h[(size_t)bi * Hd + k];
  __syncthreads();
  int o  = threadIdx.x & 31;
  int ch = threadIdx.x >> 5;
  float p = 0.0f;
  if (o < NOUT) {
    int k0 = ch * (Hd / 8);
    for (int k = k0; k < k0 + (Hd / 8); ++k)
      p += hs[k] * Wd[(size_t)k * NOUT + o];
  }
  red[ch][o] = p;
  __syncthreads();
  if (threadIdx.x < NOUT) {
    float s = bd[threadIdx.x];
    for (int c2 = 0; c2 < 8; ++c2) s += red[c2][threadIdx.x];
    y[(size_t)bi * NOUT + threadIdx.x] = s;
  }
}

// ---------------------------------------------------------------------------

extern "C" void kernel_launch(void* const* d_in, const int* in_sizes, int n_in,
                              void* d_out, int out_size, void* d_ws, size_t ws_size,
                              hipStream_t stream) {
  const float* x  = (const float*)d_in[0];
  const float* W  = (const float*)d_in[1];
  const float* U  = (const float*)d_in[2];
  const float* b  = (const float*)d_in[3];
  const float* Wd = (const float*)d_in[4];
  const float* bd = (const float*)d_in[5];
  float* y = (float*)d_out;

  char* ws = (char*)d_ws;
  _Float16* xp  = (_Float16*)ws; ws += (size_t)Tseq * Bsz * KXP * 2;  // 31.5 MB
  _Float16* Wpt = (_Float16*)ws; ws += (size_t)G4 * KXP * 2;          // 1.05 MB
  _Float16* Upt = (_Float16*)ws; ws += (size_t)G4 * Hd * 2;           // 8.4 MB
  _Float16* hb0 = (_Float16*)ws; ws += (size_t)Bsz * Hd * 2;          // 4.2 MB
  _Float16* hb1 = (_Float16*)ws; ws += (size_t)Bsz * Hd * 2;          // 4.2 MB
  float*    cst = (float*)ws;    ws += (size_t)Bsz * Hd * 4;          // 8.4 MB

  convert_x<<<(Tseq * Bsz * KXP) / 256, 256, 0, stream>>>(x, xp);
  transpose_W<<<dim3(G4 / 32, KXP / 32), dim3(32, 8), 0, stream>>>(W, Wpt);
  transpose_U<<<dim3(G4 / 32, Hd / 32), dim3(32, 8), 0, stream>>>(U, Upt);

  for (int t = 0; t < Tseq; ++t) {
    const _Float16* hin  = ((t - 1) & 1) ? hb1 : hb0;   // unused at t=0
    _Float16*       hout = (t & 1) ? hb1 : hb0;
    lstm_step<<<dim3((Bsz / 128) * (G4 / 128)), 256, 0, stream>>>(
        xp + (size_t)t * (Bsz * KXP), Wpt, Upt, b,
        (t == 0) ? hb0 : hin, hout, cst, (t == 0) ? 1 : 0);
  }

  // h_{59} is in hb1 (59 & 1 == 1)
  final_dense<<<Bsz, 256, 0, stream>>>(hb1, Wd, bd, y);
}

// Round 5
// 1723.005 us; speedup vs baseline: 1.6867x; 1.6867x over previous
//
#include <hip/hip_runtime.h>
#include <cstdint>
#include <cstddef>

#define Bsz 2048
#define Tseq 60
#define Fin 89
#define Hd 1024
#define G4 4096
#define KXP 128   // x/W K padded to 2x BK=64 so all rounds are uniform
#define NOUT 30

typedef _Float16 half8 __attribute__((ext_vector_type(8)));
typedef float f32x4 __attribute__((ext_vector_type(4)));

__device__ __forceinline__ void gload_lds16(const void* g, void* l) {
  __builtin_amdgcn_global_load_lds((const __attribute__((address_space(1))) void*)g,
                                   (__attribute__((address_space(3))) void*)l,
                                   16, 0, 0);
}

__device__ __forceinline__ float sigmoidf_fast(float x) {
  return 1.0f / (1.0f + __expf(-x));
}

// ---------------------------------------------------------------------------
// Prep kernels (run once per launch; ws is re-poisoned before every call)
// ---------------------------------------------------------------------------

// x [B][T][Fin] fp32 -> xp [T][B][KXP] fp16, zero-padded k in [Fin, KXP)
__global__ __launch_bounds__(256) void convert_x(const float* __restrict__ x,
                                                 _Float16* __restrict__ xp) {
  int idx = blockIdx.x * 256 + threadIdx.x;   // < Tseq*Bsz*KXP
  int k = idx % KXP;
  int b = (idx / KXP) % Bsz;
  int t = idx / (KXP * Bsz);
  float v = (k < Fin) ? x[((size_t)b * Tseq + t) * Fin + k] : 0.0f;
  xp[idx] = (_Float16)v;
}

// W [Fin][G4] fp32 -> Wpt [G4][KXP] fp16 (B^T layout, zero rows k>=Fin)
__global__ __launch_bounds__(256) void transpose_W(const float* __restrict__ W,
                                                   _Float16* __restrict__ Wpt) {
  __shared__ float tile[32][33];
  int n0 = blockIdx.x * 32;
  int k0 = blockIdx.y * 32;
  int tx = threadIdx.x, ty = threadIdx.y;
  for (int i = ty; i < 32; i += 8) {
    int k = k0 + i;
    tile[i][tx] = (k < Fin) ? W[(size_t)k * G4 + n0 + tx] : 0.0f;
  }
  __syncthreads();
  for (int i = ty; i < 32; i += 8)
    Wpt[(size_t)(n0 + i) * KXP + k0 + tx] = (_Float16)tile[tx][i];
}

// U [Hd][G4] fp32 -> Upt [G4][Hd] fp16 (B^T layout)
__global__ __launch_bounds__(256) void transpose_U(const float* __restrict__ U,
                                                   _Float16* __restrict__ Upt) {
  __shared__ float tile[32][33];
  int n0 = blockIdx.x * 32;
  int k0 = blockIdx.y * 32;
  int tx = threadIdx.x, ty = threadIdx.y;
  for (int i = ty; i < 32; i += 8)
    tile[i][tx] = U[(size_t)(k0 + i) * G4 + n0 + tx];
  __syncthreads();
  for (int i = ty; i < 32; i += 8)
    Upt[(size_t)(n0 + i) * Hd + k0 + tx] = (_Float16)tile[tx][i];
}

// ---------------------------------------------------------------------------
// One LSTM step. Block tile: 128 batch rows x [4 gates x 32 hidden units].
// 4 waves: wave w -> rows 64*(w>>1)..+63, hidden units j0+16*(w&1)..+15,
// all 4 gates. Each lane holds (i,f,g,o) of one hidden unit in registers;
// epilogue is shuffle-free.
//
// Round-3 post-mortem design (unchanged; round 4 was an infra timeout):
//   - A and B both DMA-staged (A-to-registers regressed: scattered per-lane
//     loads flooded TA with 2x line-requests + 2x redundancy -> 52 us/step).
//   - Fragment reads are inline-asm ds_read_b128: rounds 1 vs 2 timed
//     IDENTICAL (drain-0 vs counted-vmcnt), proving hipcc inserted its own
//     conservative vmcnt(0) before C++ ds_reads that alias DMA-written LDS.
//     Asm reads are opaque -> the hand-counted `s_waitcnt vmcnt(8)` becomes
//     the ONLY B-DMA wait, and prefetched DMA truly stays in flight.
//   - Split-st waits: issue all 16 reads, lgkmcnt(8) -> 16 MFMA (st0),
//     lgkmcnt(0) -> 16 MFMA (st1): st1-read latency hides under st0 MFMAs.
//   - Square XCD swizzle: each XCD owns 8 m-panels x 8 j-panels -> per-XCD
//     per-step L2 stream 2.4 MB (was 4.7), U-slice 2.1 MB stays L2-resident
//     across steps.
//
// LDS layout (conflict-free, DMA-compatible): 16-row unit = 16 rows x
// 32 halfs = 1 KB; slot s of row r holds global chunk s ^ ((r>>1)&3);
// fragment read slot sA = quad ^ ((l16>>1)&3) -> the wave's 64 reads form a
// perfect permutation of the unit, 2 accesses/bank (m136).
// ---------------------------------------------------------------------------
__global__ __launch_bounds__(256, 2) void lstm_step(
    const _Float16* __restrict__ xp_t,  // [Bsz][KXP]  (this timestep)
    const _Float16* __restrict__ Wpt,   // [G4][KXP]   (B^T)
    const _Float16* __restrict__ Upt,   // [G4][Hd]    (B^T)
    const float*    __restrict__ bias,  // [G4]
    const _Float16* __restrict__ h_in,  // [Bsz][Hd]
    _Float16*       __restrict__ h_out, // [Bsz][Hd]
    float*          __restrict__ cst,   // [Bsz][Hd]
    int skip_h)                          // t==0: only x@W, c_prev = 0
{
  __shared__ __align__(16) _Float16 As[2 * 8192];  // 2 buf x (2 subtiles x 8 units)
  __shared__ __align__(16) _Float16 Bs[2 * 8192];

  const int tid  = threadIdx.x;
  const int wave = tid >> 6;
  const int lane = tid & 63;
  const int quad = lane >> 4;
  const int l16  = lane & 15;

  // Square XCD swizzle (512 blocks, 8 XCDs round-robin dispatch):
  // XCD x owns m-panels 8*(x&1)..+7  x  j-panels 8*(x>>1)..+7  (bijective).
  const int id  = blockIdx.x;
  const int xcd = id & 7, loc = id >> 3;          // loc in [0,64)
  const int m0 = (((xcd & 1) << 3) + (loc & 7)) * 128;   // batch-row base
  const int j0 = (((xcd >> 1) << 3) + (loc >> 3)) * 32;  // hidden-unit base

  const int srow = lane >> 2;                      // staging row in unit
  const int qg   = (lane & 3) ^ ((lane >> 3) & 3); // staging global chunk
  const int sA   = quad ^ ((l16 >> 1) & 3);        // fragment LDS slot

  const int hb    = 16 * (wave & 1);
  const int mwave = 64 * (wave >> 1);
  const int j  = j0 + hb + l16;
  const int uA = 4 * (wave >> 1);     // A fragment unit base (+mi)
  const int uB = wave & 1;            // B fragment unit base (2p + uB)
  const int aoff = l16 * 32 + sA * 8; // fragment offset within unit (halfs)

  float bv[4];
  for (int p = 0; p < 4; ++p) bv[p] = bias[p * Hd + j];

  f32x4 acc[4][4];
  for (int mi = 0; mi < 4; ++mi)
    for (int p = 0; p < 4; ++p)
      acc[mi][p] = f32x4{bv[p], bv[p], bv[p], bv[p]};

  // stage one round's 32 KB (A+B tiles) into buffer `buf` (async DMA).
  // Exactly 8 global_load_lds per WAVE (4 A + 4 B) -> vmcnt granularity = 8.
  auto stage = [&](int buf, int r) {
    const _Float16* Ab; const _Float16* Bb; int strA, strB, k0;
    if (r < 2) { Ab = xp_t; strA = KXP; Bb = Wpt; strB = KXP; k0 = r * 64; }
    else       { Ab = h_in; strA = Hd;  Bb = Upt; strB = Hd;  k0 = (r - 2) * 64; }
    _Float16* Ad = &As[buf * 8192];
    _Float16* Bd = &Bs[buf * 8192];
#pragma unroll
    for (int ii = 0; ii < 4; ++ii) {
      int i = ii * 4 + wave;        // 0..15
      int st = i >> 3, ci = i & 7;
      gload_lds16(Ab + (size_t)(m0 + ci * 16 + srow) * strA + k0 + st * 32 + qg * 8,
                  Ad + st * 4096 + ci * 512);
    }
#pragma unroll
    for (int ii = 0; ii < 4; ++ii) {
      int i = ii * 4 + wave;
      int st = i >> 3, ci = i & 7;
      int ln = ci * 16 + srow;
      int gn = (ln >> 5) * Hd + j0 + (ln & 31);   // gate-major B rows
      gload_lds16(Bb + (size_t)gn * strB + k0 + st * 32 + qg * 8,
                  Bd + st * 4096 + ci * 512);
    }
  };

  // consume buffer `buf`: 16 asm ds_read_b128 (compiler-opaque) + 32 MFMA,
  // split per k-subtile so st1-read latency hides under st0 MFMAs.
  auto compute = [&](int buf) {
    const __attribute__((address_space(3))) _Float16* As3 =
        (const __attribute__((address_space(3))) _Float16*)&As[buf * 8192];
    const __attribute__((address_space(3))) _Float16* Bs3 =
        (const __attribute__((address_space(3))) _Float16*)&Bs[buf * 8192];
    half8 a0[4], b0[4], a1[4], b1[4];
#pragma unroll
    for (int mi = 0; mi < 4; ++mi)
      asm volatile("ds_read_b128 %0, %1" : "=v"(a0[mi])
                   : "v"(As3 + (uA + mi) * 512 + aoff) : "memory");
#pragma unroll
    for (int p = 0; p < 4; ++p)
      asm volatile("ds_read_b128 %0, %1" : "=v"(b0[p])
                   : "v"(Bs3 + (2 * p + uB) * 512 + aoff) : "memory");
#pragma unroll
    for (int mi = 0; mi < 4; ++mi)
      asm volatile("ds_read_b128 %0, %1" : "=v"(a1[mi])
                   : "v"(As3 + 4096 + (uA + mi) * 512 + aoff) : "memory");
#pragma unroll
    for (int p = 0; p < 4; ++p)
      asm volatile("ds_read_b128 %0, %1" : "=v"(b1[p])
                   : "v"(Bs3 + 4096 + (2 * p + uB) * 512 + aoff) : "memory");
    asm volatile("s_waitcnt lgkmcnt(8)" ::: "memory");
    __builtin_amdgcn_sched_barrier(0);   // rule #18: pin MFMAs below the wait
#pragma unroll
    for (int mi = 0; mi < 4; ++mi)
#pragma unroll
      for (int p = 0; p < 4; ++p)
        acc[mi][p] = __builtin_amdgcn_mfma_f32_16x16x32_f16(a0[mi], b0[p],
                                                            acc[mi][p], 0, 0, 0);
    asm volatile("s_waitcnt lgkmcnt(0)" ::: "memory");
    __builtin_amdgcn_sched_barrier(0);
#pragma unroll
    for (int mi = 0; mi < 4; ++mi)
#pragma unroll
      for (int p = 0; p < 4; ++p)
        acc[mi][p] = __builtin_amdgcn_mfma_f32_16x16x32_f16(a1[mi], b1[p],
                                                            acc[mi][p], 0, 0, 0);
  };

  const int NR = skip_h ? 2 : 18;

  stage(0, 0);
  stage(1, 1);                        // 16 VMEM in flight per wave
  for (int r = 0; r < NR; ++r) {
    const int cur = r & 1;
    // wait for THIS buffer's 8 DMA loads; keep next buffer's 8 in flight.
    if (r < NR - 1) {
      asm volatile("s_waitcnt vmcnt(8)" ::: "memory");
    } else {
      asm volatile("s_waitcnt vmcnt(0)" ::: "memory");
    }
    __builtin_amdgcn_sched_barrier(0);
    __builtin_amdgcn_s_barrier();     // all waves: buf `cur` landed
    __builtin_amdgcn_s_setprio(1);
    compute(cur);                     // ends with lgkmcnt(0): reads consumed
    __builtin_amdgcn_s_setprio(0);
    __builtin_amdgcn_s_barrier();     // all waves done reading buf `cur`
    if (r + 2 < NR) stage(cur, r + 2);  // restage; stays in flight next round
  }

  // epilogue: lane holds i,f,g,o for hidden unit j, rows quad*4+r (m89 layout)
  for (int mi = 0; mi < 4; ++mi) {
    for (int r = 0; r < 4; ++r) {
      int row = m0 + mwave + mi * 16 + quad * 4 + r;
      size_t idx = (size_t)row * Hd + j;
      float iv = sigmoidf_fast(acc[mi][0][r]);
      float fv = sigmoidf_fast(acc[mi][1][r]);
      float gv = fmaxf(acc[mi][2][r], 0.0f);   // relu candidate
      float ov = sigmoidf_fast(acc[mi][3][r]);
      float cprev = skip_h ? 0.0f : cst[idx];  // c_0 = 0 folded in
      float cv = fv * cprev + iv * gv;
      cst[idx] = cv;
      float hv = ov * fmaxf(cv, 0.0f);         // relu on cell output
      h_out[idx] = (_Float16)hv;
    }
  }
}

// ---------------------------------------------------------------------------
// y[b][o] = bd[o] + sum_k h[b][k] * Wd[k][o]
// ---------------------------------------------------------------------------
__global__ __launch_bounds__(256) void final_dense(const _Float16* __restrict__ h,
                                                   const float* __restrict__ Wd,
                                                   const float* __restrict__ bd,
                                                   float* __restrict__ y) {
  __shared__ float hs[Hd];
  __shared__ float red[8][32];
  int bi = blockIdx.x;
  for (int k = threadIdx.x; k < Hd; k += 256)
    hs[k] = (float)h[(size_t)bi * Hd + k];
  __syncthreads();
  int o  = threadIdx.x & 31;
  int ch = threadIdx.x >> 5;
  float p = 0.0f;
  if (o < NOUT) {
    int k0 = ch * (Hd / 8);
    for (int k = k0; k < k0 + (Hd / 8); ++k)
      p += hs[k] * Wd[(size_t)k * NOUT + o];
  }
  red[ch][o] = p;
  __syncthreads();
  if (threadIdx.x < NOUT) {
    float s = bd[threadIdx.x];
    for (int c2 = 0; c2 < 8; ++c2) s += red[c2][threadIdx.x];
    y[(size_t)bi * NOUT + threadIdx.x] = s;
  }
}

// ---------------------------------------------------------------------------

extern "C" void kernel_launch(void* const* d_in, const int* in_sizes, int n_in,
                              void* d_out, int out_size, void* d_ws, size_t ws_size,
                              hipStream_t stream) {
  const float* x  = (const float*)d_in[0];
  const float* W  = (const float*)d_in[1];
  const float* U  = (const float*)d_in[2];
  const float* b  = (const float*)d_in[3];
  const float* Wd = (const float*)d_in[4];
  const float* bd = (const float*)d_in[5];
  float* y = (float*)d_out;

  char* ws = (char*)d_ws;
  _Float16* xp  = (_Float16*)ws; ws += (size_t)Tseq * Bsz * KXP * 2;  // 31.5 MB
  _Float16* Wpt = (_Float16*)ws; ws += (size_t)G4 * KXP * 2;          // 1.05 MB
  _Float16* Upt = (_Float16*)ws; ws += (size_t)G4 * Hd * 2;           // 8.4 MB
  _Float16* hb0 = (_Float16*)ws; ws += (size_t)Bsz * Hd * 2;          // 4.2 MB
  _Float16* hb1 = (_Float16*)ws; ws += (size_t)Bsz * Hd * 2;          // 4.2 MB
  float*    cst = (float*)ws;    ws += (size_t)Bsz * Hd * 4;          // 8.4 MB

  convert_x<<<(Tseq * Bsz * KXP) / 256, 256, 0, stream>>>(x, xp);
  transpose_W<<<dim3(G4 / 32, KXP / 32), dim3(32, 8), 0, stream>>>(W, Wpt);
  transpose_U<<<dim3(G4 / 32, Hd / 32), dim3(32, 8), 0, stream>>>(U, Upt);

  for (int t = 0; t < Tseq; ++t) {
    const _Float16* hin  = ((t - 1) & 1) ? hb1 : hb0;   // unused at t=0
    _Float16*       hout = (t & 1) ? hb1 : hb0;
    lstm_step<<<dim3((Bsz / 128) * (G4 / 128)), 256, 0, stream>>>(
        xp + (size_t)t * (Bsz * KXP), Wpt, Upt, b,
        (t == 0) ? hb0 : hin, hout, cst, (t == 0) ? 1 : 0);
  }

  // h_{59} is in hb1 (59 & 1 == 1)
  final_dense<<<Bsz, 256, 0, stream>>>(hb1, Wd, bd, y);
}